// Round 4
// baseline (1412.164 us; speedup 1.0000x reference)
//
#include <hip/hip_runtime.h>
#include <hip/hip_bf16.h>
#include <math.h>

// MoE: T=8192 tokens, D=1024, MLP=4096, E=8, top-2.
// Round 4: 128x256 tiles in both fused GEMMs (acc 4x8); gemm2 gets an
// XCD-local block swizzle so a slot-panel's 4 col-blocks share one XCD L2
// (bid%8 == y%8, consecutive slots). Inner loop (m97 recipe) unchanged.

#define T_TOKENS 8192
#define DIM 1024
#define MLP 4096
#define NEXP 8
#define MAXSLOT 17408   // 136 row-blocks * 128
#define MAXYB 136

using bf16 = __hip_bfloat16;
typedef __attribute__((ext_vector_type(8))) short short8v;
typedef __attribute__((ext_vector_type(4))) float float4v;

__device__ __forceinline__ void gl2lds16(const void* g, void* l) {
  __builtin_amdgcn_global_load_lds(
      (const __attribute__((address_space(1))) unsigned int*)g,
      (__attribute__((address_space(3))) unsigned int*)l, 16, 0, 0);
}

// ---------------- router + x->bf16 convert (fused) ----------------
__global__ __launch_bounds__(256) void router_convert(
    const float* __restrict__ x, const float* __restrict__ rw,
    const float* __restrict__ rb, const float* __restrict__ eb,
    bf16* __restrict__ xb, int4* __restrict__ tokinfo) {
  __shared__ float rws[NEXP][DIM];
  __shared__ float rbe[NEXP];
  for (int i = threadIdx.x; i < NEXP * DIM; i += 256)
    rws[i & 7][i >> 3] = rw[i];
  if (threadIdx.x < NEXP) rbe[threadIdx.x] = rb[threadIdx.x] + eb[threadIdx.x];
  __syncthreads();
  int wave = threadIdx.x >> 6, lane = threadIdx.x & 63;
  for (int i = 0; i < 4; i++) {
    int t = blockIdx.x * 16 + wave * 4 + i;
    const float4* xr = (const float4*)(x + (size_t)t * DIM);
    float acc[NEXP];
#pragma unroll
    for (int e = 0; e < NEXP; e++) acc[e] = 0.f;
#pragma unroll
    for (int it = 0; it < 4; it++) {
      float4 xv = xr[it * 64 + lane];
      union { bf16 h[4]; uint2 u; } o;
      o.h[0] = __float2bfloat16(xv.x);
      o.h[1] = __float2bfloat16(xv.y);
      o.h[2] = __float2bfloat16(xv.z);
      o.h[3] = __float2bfloat16(xv.w);
      *(uint2*)(xb + (size_t)t * DIM + (it * 64 + lane) * 4) = o.u;
#pragma unroll
      for (int e = 0; e < NEXP; e++) {
        float4 rv = ((const float4*)rws[e])[it * 64 + lane];
        acc[e] += xv.x * rv.x + xv.y * rv.y + xv.z * rv.z + xv.w * rv.w;
      }
    }
#pragma unroll
    for (int e = 0; e < NEXP; e++) {
#pragma unroll
      for (int off = 32; off > 0; off >>= 1) acc[e] += __shfl_xor(acc[e], off, 64);
    }
    if (lane == 0) {
      float l[NEXP], m = -1e30f;
#pragma unroll
      for (int e = 0; e < NEXP; e++) { l[e] = acc[e] + rbe[e]; m = fmaxf(m, l[e]); }
      float p[NEXP], s = 0.f;
#pragma unroll
      for (int e = 0; e < NEXP; e++) { p[e] = expf(l[e] - m); s += p[e]; }
      float inv = 1.f / s;
#pragma unroll
      for (int e = 0; e < NEXP; e++) p[e] *= inv;
      int i0 = 0;
#pragma unroll
      for (int e = 1; e < NEXP; e++) if (p[e] > p[i0]) i0 = e;
      int i1 = (i0 == 0) ? 1 : 0;
#pragma unroll
      for (int e = 0; e < NEXP; e++) if (e != i0 && p[e] > p[i1]) i1 = e;
      float sn = p[i0] + p[i1] + 1e-9f;
      tokinfo[t] = make_int4(i0, i1, __float_as_int(p[i0] / sn),
                             __float_as_int(p[i1] / sn));
    }
  }
}

// ---------------- build per-expert lists ----------------
__global__ __launch_bounds__(256) void build_lists(
    const int4* __restrict__ tokinfo, int* __restrict__ counts,
    int* __restrict__ toks, float* __restrict__ gates) {
  __shared__ int hist[NEXP], base[NEXP];
  if (threadIdx.x < NEXP) hist[threadIdx.x] = 0;
  __syncthreads();
  int t = blockIdx.x * 256 + threadIdx.x;
  int4 info = tokinfo[t];
  int r0 = atomicAdd(&hist[info.x], 1);
  int r1 = atomicAdd(&hist[info.y], 1);
  __syncthreads();
  if (threadIdx.x < NEXP)
    base[threadIdx.x] = atomicAdd(&counts[threadIdx.x * 16], hist[threadIdx.x]);
  __syncthreads();
  int p0 = base[info.x] + r0, p1 = base[info.y] + r1;
  toks[info.x * T_TOKENS + p0] = t;
  gates[info.x * T_TOKENS + p0] = __int_as_float(info.z);
  toks[info.y * T_TOKENS + p1] = t;
  gates[info.y * T_TOKENS + p1] = __int_as_float(info.w);
}

// ---------------- meta: 128-aligned block offsets per expert --------------
__global__ void compute_meta(const int* __restrict__ counts, int* __restrict__ meta) {
  if (threadIdx.x == 0 && blockIdx.x == 0) {
    int off = 0;
    for (int e = 0; e < NEXP; e++) {
      meta[e] = off;
      int c = counts[e * 16];
      meta[16 + e] = c;
      off += (c + 127) >> 7;
    }
    meta[8] = off;
  }
}

// ---------------- W [K][N] fp32 -> Wt [N][K] bf16, per-z expert -----------
__global__ __launch_bounds__(256) void transpose_cvt64(
    const float* __restrict__ W, bf16* __restrict__ Wt, int K, int N) {
  W += (size_t)blockIdx.z * K * N;
  Wt += (size_t)blockIdx.z * K * N;
  __shared__ float tile[64][65];
  int bn = blockIdx.x * 64, bk = blockIdx.y * 64;
  int tx = threadIdx.x & 15, ty = threadIdx.x >> 4;
#pragma unroll
  for (int j = 0; j < 4; j++) {
    int k = bk + ty + j * 16;
    float4 v = *(const float4*)(W + (size_t)k * N + bn + tx * 4);
    tile[ty + j * 16][tx * 4 + 0] = v.x;
    tile[ty + j * 16][tx * 4 + 1] = v.y;
    tile[ty + j * 16][tx * 4 + 2] = v.z;
    tile[ty + j * 16][tx * 4 + 3] = v.w;
  }
  __syncthreads();
#pragma unroll
  for (int j = 0; j < 4; j++) {
    int n = bn + ty + j * 16;
    union { bf16 h[4]; uint2 u; } o;
    o.h[0] = __float2bfloat16(tile[tx * 4 + 0][ty + j * 16]);
    o.h[1] = __float2bfloat16(tile[tx * 4 + 1][ty + j * 16]);
    o.h[2] = __float2bfloat16(tile[tx * 4 + 2][ty + j * 16]);
    o.h[3] = __float2bfloat16(tile[tx * 4 + 3][ty + j * 16]);
    *(uint2*)(Wt + (size_t)n * K + bk + tx * 4) = o.u;
  }
}

// ================= FUSED GEMMs, 128x256 tiles =================
// GEMM1: H[slot] = gelu(X[tok] @ W1[e] + b1[e]); grid (MLP/256, MAXYB)
__global__ __launch_bounds__(256) void moe_gemm1_f(
    const bf16* __restrict__ Xb, const bf16* __restrict__ Wt,
    const float* __restrict__ b1, bf16* __restrict__ H,
    const int* __restrict__ toks, const int* __restrict__ meta) {
  __shared__ __align__(16) bf16 As[128][32];   // 8 KB
  __shared__ __align__(16) bf16 Bs[256][32];   // 16 KB
  __shared__ int tids[128];
  __shared__ int smeta[24];
  int tid = threadIdx.x;
  if (tid < 24) smeta[tid] = meta[tid];
  __syncthreads();
  int y = blockIdx.y;
  if (y >= smeta[8]) return;
  int e = 0;
#pragma unroll
  for (int k = 1; k < NEXP; k++) if (y >= smeta[k]) e = k;
  int ne = smeta[16 + e];
  int row0 = (y - smeta[e]) * 128;
  int col0 = blockIdx.x * 256;
  const bf16* Wte = Wt + (size_t)e * MLP * DIM;
  const float* bias = b1 + e * MLP;
  const int* tokse = toks + e * T_TOKENS;

  if (tid < 128) {
    int r = row0 + tid;
    tids[tid] = tokse[r < ne ? r : ne - 1];
  }
  __syncthreads();

  int wave = tid >> 6, lane = tid & 63;
  int wr = (wave >> 1) * 64, wc = (wave & 1) * 128;
  int lr = lane & 15, quad = lane >> 4;
  int r0 = tid >> 2, seg = tid & 3;

  const bf16* pA0 = Xb + (size_t)tids[r0] * DIM + seg * 8;
  const bf16* pA1 = Xb + (size_t)tids[64 + r0] * DIM + seg * 8;
  const bf16* pB0 = Wte + (size_t)(col0 + r0) * DIM + seg * 8;
  const bf16* pB1 = pB0 + (size_t)64 * DIM;
  const bf16* pB2 = pB0 + (size_t)128 * DIM;
  const bf16* pB3 = pB0 + (size_t)192 * DIM;
  char* lA = (char*)As + wave * 1024;
  char* lB = (char*)Bs + wave * 1024;

  float4v acc[4][8];
#pragma unroll
  for (int i = 0; i < 4; i++)
#pragma unroll
    for (int j = 0; j < 8; j++) acc[i][j] = (float4v)0.0f;

  for (int k0 = 0; k0 < DIM; k0 += 32) {
    gl2lds16(pA0 + k0, lA);
    gl2lds16(pA1 + k0, lA + 4096);
    gl2lds16(pB0 + k0, lB);
    gl2lds16(pB1 + k0, lB + 4096);
    gl2lds16(pB2 + k0, lB + 8192);
    gl2lds16(pB3 + k0, lB + 12288);
    __syncthreads();
    short8v a[4], b[8];
#pragma unroll
    for (int mt = 0; mt < 4; mt++)
      a[mt] = *(const short8v*)&As[wr + mt * 16 + lr][quad * 8];
#pragma unroll
    for (int nt = 0; nt < 8; nt++)
      b[nt] = *(const short8v*)&Bs[wc + nt * 16 + lr][quad * 8];
#pragma unroll
    for (int mt = 0; mt < 4; mt++)
#pragma unroll
      for (int nt = 0; nt < 8; nt++)
        acc[mt][nt] = __builtin_amdgcn_mfma_f32_16x16x32_bf16(a[mt], b[nt],
                                                              acc[mt][nt], 0, 0, 0);
    __syncthreads();
  }

#pragma unroll
  for (int mt = 0; mt < 4; mt++) {
#pragma unroll
    for (int r = 0; r < 4; r++) {
      int gr = wr + mt * 16 + quad * 4 + r;
      if (row0 + gr < ne) {
#pragma unroll
        for (int nt = 0; nt < 8; nt++) {
          int gc = col0 + wc + nt * 16 + lr;
          float v = acc[mt][nt][r] + bias[gc];
          v = 0.5f * v * (1.0f + erff(v * 0.70710678118f));
          H[(size_t)(y * 128 + gr) * MLP + gc] = __float2bfloat16(v);
        }
      }
    }
  }
}

// GEMM2: out[tok] += g * (H[slot] @ W2[e] + b2[e]); 1-D grid 544, swizzled:
// y = 8*(bid>>5)+(bid&7), x = (bid>>3)&3  -> bid%8 == y%8 (XCD-local panels)
__global__ __launch_bounds__(256) void moe_gemm2_f(
    const bf16* __restrict__ H, const bf16* __restrict__ Wt,
    const float* __restrict__ b2, float* __restrict__ out,
    const int* __restrict__ toks, const float* __restrict__ gates,
    const int* __restrict__ meta) {
  __shared__ __align__(16) bf16 As[128][32];   // 8 KB
  __shared__ __align__(16) bf16 Bs[256][32];   // 16 KB
  __shared__ int smeta[24];
  int tid = threadIdx.x;
  if (tid < 24) smeta[tid] = meta[tid];
  __syncthreads();
  int bid = blockIdx.x;
  int y = ((bid >> 5) << 3) + (bid & 7);
  int x = (bid >> 3) & 3;
  if (y >= smeta[8]) return;
  int e = 0;
#pragma unroll
  for (int k = 1; k < NEXP; k++) if (y >= smeta[k]) e = k;
  int ne = smeta[16 + e];
  int row0 = (y - smeta[e]) * 128;
  int col0 = x * 256;
  const bf16* Wte = Wt + (size_t)e * DIM * MLP;
  const float* bias = b2 + e * DIM;
  const int* tokse = toks + e * T_TOKENS;
  const float* gatese = gates + e * T_TOKENS;

  int wave = tid >> 6, lane = tid & 63;
  int wr = (wave >> 1) * 64, wc = (wave & 1) * 128;
  int lr = lane & 15, quad = lane >> 4;
  int r0 = tid >> 2, seg = tid & 3;

  const bf16* pA0 = H + (size_t)(y * 128 + r0) * MLP + seg * 8;
  const bf16* pA1 = H + (size_t)(y * 128 + 64 + r0) * MLP + seg * 8;
  const bf16* pB0 = Wte + (size_t)(col0 + r0) * MLP + seg * 8;
  const bf16* pB1 = pB0 + (size_t)64 * MLP;
  const bf16* pB2 = pB0 + (size_t)128 * MLP;
  const bf16* pB3 = pB0 + (size_t)192 * MLP;
  char* lA = (char*)As + wave * 1024;
  char* lB = (char*)Bs + wave * 1024;

  float4v acc[4][8];
#pragma unroll
  for (int i = 0; i < 4; i++)
#pragma unroll
    for (int j = 0; j < 8; j++) acc[i][j] = (float4v)0.0f;

  for (int k0 = 0; k0 < MLP; k0 += 32) {
    gl2lds16(pA0 + k0, lA);
    gl2lds16(pA1 + k0, lA + 4096);
    gl2lds16(pB0 + k0, lB);
    gl2lds16(pB1 + k0, lB + 4096);
    gl2lds16(pB2 + k0, lB + 8192);
    gl2lds16(pB3 + k0, lB + 12288);
    __syncthreads();
    short8v a[4], b[8];
#pragma unroll
    for (int mt = 0; mt < 4; mt++)
      a[mt] = *(const short8v*)&As[wr + mt * 16 + lr][quad * 8];
#pragma unroll
    for (int nt = 0; nt < 8; nt++)
      b[nt] = *(const short8v*)&Bs[wc + nt * 16 + lr][quad * 8];
#pragma unroll
    for (int mt = 0; mt < 4; mt++)
#pragma unroll
      for (int nt = 0; nt < 8; nt++)
        acc[mt][nt] = __builtin_amdgcn_mfma_f32_16x16x32_bf16(a[mt], b[nt],
                                                              acc[mt][nt], 0, 0, 0);
    __syncthreads();
  }

#pragma unroll
  for (int mt = 0; mt < 4; mt++) {
#pragma unroll
    for (int r = 0; r < 4; r++) {
      int gr = wr + mt * 16 + quad * 4 + r;
      int grow = row0 + gr;
      if (grow < ne) {
        int t = tokse[grow];
        float g = gatese[grow];
#pragma unroll
        for (int nt = 0; nt < 8; nt++) {
          int gc = col0 + wc + nt * 16 + lr;
          atomicAdd(&out[(size_t)t * DIM + gc], g * (acc[mt][nt][r] + bias[gc]));
        }
      }
    }
  }
}

// ================= SEQUENTIAL FALLBACK (proven, only if ws too small) ======
__global__ __launch_bounds__(256) void moe_gemm1_s(
    const bf16* __restrict__ Xb, const bf16* __restrict__ Wt,
    const float* __restrict__ bias, bf16* __restrict__ H,
    const int* __restrict__ toks, const int* __restrict__ cntp) {
  int ne = *cntp;
  int row0 = blockIdx.y * 128;
  if (row0 >= ne) return;
  int col0 = blockIdx.x * 128;
  __shared__ __align__(16) bf16 As[128][32];
  __shared__ __align__(16) bf16 Bs[128][32];
  __shared__ int tids[128];
  int tid = threadIdx.x;
  if (tid < 128) {
    int r = row0 + tid;
    tids[tid] = toks[r < ne ? r : ne - 1];
  }
  __syncthreads();
  int wave = tid >> 6, lane = tid & 63;
  int wr = (wave >> 1) * 64, wc = (wave & 1) * 64;
  int lr = lane & 15, quad = lane >> 4;
  int r0 = tid >> 2, seg = tid & 3;
  const bf16* pA0 = Xb + (size_t)tids[r0] * DIM + seg * 8;
  const bf16* pA1 = Xb + (size_t)tids[64 + r0] * DIM + seg * 8;
  const bf16* pB0 = Wt + (size_t)(col0 + r0) * DIM + seg * 8;
  const bf16* pB1 = Wt + (size_t)(col0 + 64 + r0) * DIM + seg * 8;
  char* lA = (char*)As + wave * 1024;
  char* lB = (char*)Bs + wave * 1024;
  float4v acc[4][4];
#pragma unroll
  for (int i = 0; i < 4; i++)
#pragma unroll
    for (int j = 0; j < 4; j++) acc[i][j] = (float4v)0.0f;
  for (int k0 = 0; k0 < DIM; k0 += 32) {
    gl2lds16(pA0 + k0, lA);
    gl2lds16(pA1 + k0, lA + 4096);
    gl2lds16(pB0 + k0, lB);
    gl2lds16(pB1 + k0, lB + 4096);
    __syncthreads();
    short8v a[4], b[4];
#pragma unroll
    for (int mt = 0; mt < 4; mt++)
      a[mt] = *(const short8v*)&As[wr + mt * 16 + lr][quad * 8];
#pragma unroll
    for (int nt = 0; nt < 4; nt++)
      b[nt] = *(const short8v*)&Bs[wc + nt * 16 + lr][quad * 8];
#pragma unroll
    for (int mt = 0; mt < 4; mt++)
#pragma unroll
      for (int nt = 0; nt < 4; nt++)
        acc[mt][nt] = __builtin_amdgcn_mfma_f32_16x16x32_bf16(a[mt], b[nt],
                                                              acc[mt][nt], 0, 0, 0);
    __syncthreads();
  }
#pragma unroll
  for (int mt = 0; mt < 4; mt++) {
#pragma unroll
    for (int r = 0; r < 4; r++) {
      int gr = wr + mt * 16 + quad * 4 + r;
      if (row0 + gr < ne) {
#pragma unroll
        for (int nt = 0; nt < 4; nt++) {
          int gc = col0 + wc + nt * 16 + lr;
          float v = acc[mt][nt][r] + bias[gc];
          v = 0.5f * v * (1.0f + erff(v * 0.70710678118f));
          H[(size_t)(row0 + gr) * MLP + gc] = __float2bfloat16(v);
        }
      }
    }
  }
}

__global__ __launch_bounds__(256) void moe_gemm2_s(
    const bf16* __restrict__ H, const bf16* __restrict__ Wt,
    const float* __restrict__ bias, float* __restrict__ out,
    const int* __restrict__ toks, const float* __restrict__ gates,
    const int* __restrict__ cntp) {
  int ne = *cntp;
  int row0 = blockIdx.y * 128;
  if (row0 >= ne) return;
  int col0 = blockIdx.x * 64;
  __shared__ __align__(16) bf16 As[128][32];
  __shared__ __align__(16) bf16 Bs[64][32];
  int tid = threadIdx.x;
  int wave = tid >> 6, lane = tid & 63;
  int wr = wave * 32;
  int lr = lane & 15, quad = lane >> 4;
  int r0 = tid >> 2, seg = tid & 3;
  const bf16* pA0 = H + (size_t)(row0 + r0) * MLP + seg * 8;
  const bf16* pA1 = H + (size_t)(row0 + 64 + r0) * MLP + seg * 8;
  const bf16* pB0 = Wt + (size_t)(col0 + r0) * MLP + seg * 8;
  char* lA = (char*)As + wave * 1024;
  char* lB = (char*)Bs + wave * 1024;
  float4v acc[2][4];
#pragma unroll
  for (int i = 0; i < 2; i++)
#pragma unroll
    for (int j = 0; j < 4; j++) acc[i][j] = (float4v)0.0f;
  for (int k0 = 0; k0 < MLP; k0 += 32) {
    gl2lds16(pA0 + k0, lA);
    gl2lds16(pA1 + k0, lA + 4096);
    gl2lds16(pB0 + k0, lB);
    __syncthreads();
    short8v a[2], b[4];
#pragma unroll
    for (int mt = 0; mt < 2; mt++)
      a[mt] = *(const short8v*)&As[wr + mt * 16 + lr][quad * 8];
#pragma unroll
    for (int nt = 0; nt < 4; nt++)
      b[nt] = *(const short8v*)&Bs[nt * 16 + lr][quad * 8];
#pragma unroll
    for (int mt = 0; mt < 2; mt++)
#pragma unroll
      for (int nt = 0; nt < 4; nt++)
        acc[mt][nt] = __builtin_amdgcn_mfma_f32_16x16x32_bf16(a[mt], b[nt],
                                                              acc[mt][nt], 0, 0, 0);
    __syncthreads();
  }
#pragma unroll
  for (int mt = 0; mt < 2; mt++) {
#pragma unroll
    for (int r = 0; r < 4; r++) {
      int gr = wr + mt * 16 + quad * 4 + r;
      int grow = row0 + gr;
      if (grow < ne) {
        int t = toks[grow];
        float g = gates[grow];
#pragma unroll
        for (int nt = 0; nt < 4; nt++) {
          int gc = col0 + nt * 16 + lr;
          out[(size_t)t * DIM + gc] += g * (acc[mt][nt][r] + bias[gc]);
        }
      }
    }
  }
}

extern "C" void kernel_launch(void* const* d_in, const int* in_sizes, int n_in,
                              void* d_out, int out_size, void* d_ws, size_t ws_size,
                              hipStream_t stream) {
  const float* x  = (const float*)d_in[0];
  const float* rw = (const float*)d_in[1];
  const float* rb = (const float*)d_in[2];
  const float* eb = (const float*)d_in[3];
  const float* w1 = (const float*)d_in[4];
  const float* b1 = (const float*)d_in[5];
  const float* w2 = (const float*)d_in[6];
  const float* b2 = (const float*)d_in[7];
  float* out = (float*)d_out;
  char* ws = (char*)d_ws;

  const size_t sz_H  = (size_t)MAXSLOT * MLP * 2;
  const size_t sz_xb = (size_t)T_TOKENS * DIM * 2;
  const size_t sz_W  = (size_t)NEXP * DIM * MLP * 2;
  const size_t off_xb = sz_H, off_W = off_xb + sz_xb, off_aux = off_W + sz_W;
  const size_t aux_need = 131072 + 512 + 128 + 262144 + 262144;
  const size_t need = off_aux + aux_need;

  if (ws_size >= need) {
    bf16* Hbuf = (bf16*)ws;
    bf16* xb   = (bf16*)(ws + off_xb);
    bf16* wT   = (bf16*)(ws + off_W);   // w1t during gemm1, w2t after
    char* aux  = ws + off_aux;
    int4*  tokinfo = (int4*)aux;
    int*   counts  = (int*)(aux + 131072);
    int*   meta    = (int*)(aux + 131072 + 512);
    int*   toks    = (int*)(aux + 131072 + 512 + 128);
    float* gates   = (float*)(aux + 131072 + 512 + 128 + 262144);

    hipMemsetAsync(counts, 0, 512, stream);
    hipMemsetAsync(d_out, 0, (size_t)T_TOKENS * DIM * sizeof(float), stream);

    router_convert<<<T_TOKENS / 16, 256, 0, stream>>>(x, rw, rb, eb, xb, tokinfo);
    build_lists<<<T_TOKENS / 256, 256, 0, stream>>>(tokinfo, counts, toks, gates);
    compute_meta<<<1, 64, 0, stream>>>(counts, meta);

    transpose_cvt64<<<dim3(MLP / 64, DIM / 64, NEXP), 256, 0, stream>>>(
        w1, wT, DIM, MLP);
    moe_gemm1_f<<<dim3(MLP / 256, MAXYB), 256, 0, stream>>>(
        xb, wT, b1, Hbuf, toks, meta);
    transpose_cvt64<<<dim3(DIM / 64, MLP / 64, NEXP), 256, 0, stream>>>(
        w2, wT, MLP, DIM);
    moe_gemm2_f<<<dim3((DIM / 256) * MAXYB), 256, 0, stream>>>(
        Hbuf, wT, b2, out, toks, gates, meta);
  } else {
    bf16* xb   = (bf16*)ws;
    bf16* w1t  = (bf16*)(ws + (size_t)(16 << 20));
    bf16* w2t  = (bf16*)(ws + (size_t)(24 << 20));
    bf16* Hbuf = (bf16*)(ws + (size_t)(32 << 20));
    char* aux  = ws + (size_t)(96 << 20);
    int4*  tokinfo = (int4*)aux;
    int*   counts  = (int*)(aux + 131072);
    int*   toks    = (int*)(aux + 131072 + 512);
    float* gates   = (float*)(aux + 131072 + 512 + 262144);

    hipMemsetAsync(counts, 0, 512, stream);
    hipMemsetAsync(d_out, 0, (size_t)T_TOKENS * DIM * sizeof(float), stream);

    router_convert<<<T_TOKENS / 16, 256, 0, stream>>>(x, rw, rb, eb, xb, tokinfo);
    build_lists<<<T_TOKENS / 256, 256, 0, stream>>>(tokinfo, counts, toks, gates);

    for (int e = 0; e < NEXP; e++) {
      transpose_cvt64<<<dim3(MLP / 64, DIM / 64, 1), 256, 0, stream>>>(
          w1 + (size_t)e * DIM * MLP, w1t, DIM, MLP);
      moe_gemm1_s<<<dim3(MLP / 128, T_TOKENS / 128), 256, 0, stream>>>(
          xb, w1t, b1 + (size_t)e * MLP, Hbuf, toks + e * T_TOKENS,
          counts + e * 16);
      transpose_cvt64<<<dim3(DIM / 64, MLP / 64, 1), 256, 0, stream>>>(
          w2 + (size_t)e * MLP * DIM, w2t, MLP, DIM);
      moe_gemm2_s<<<dim3(DIM / 64, T_TOKENS / 128), 256, 0, stream>>>(
          Hbuf, w2t, b2 + (size_t)e * DIM, out, toks + e * T_TOKENS,
          gates + e * T_TOKENS, counts + e * 16);
    }
  }
}